// Round 1
// baseline (1587.619 us; speedup 1.0000x reference)
//
#include <hip/hip_runtime.h>

#define NN 20000
#define IC 128
#define OC 128
#define NSTEP 32
#define NE 256000
#define KSEL 128000
#define NCOL 544    // 512 w_v-path cols (t*16+c) + 32 p_t-folded cols
#define TOTCOL 672  // + 128 V cols
#define NPB 8       // nodes per block in k_node

struct SelState {
  unsigned long long prefix;
  unsigned r;       // remaining rank; after pass 7 == "needed" among equals
  unsigned selc;    // selected count
  unsigned done[8]; // per-pass block-done counters
};

// ---------------------------------------------------------------- init / fold
__global__ void k_init(const float* __restrict__ p_t, const float* __restrict__ lin_w,
                       const float* __restrict__ inc_w, const float* __restrict__ inc_b,
                       float* __restrict__ Wf, float* __restrict__ Wvt,
                       float* __restrict__ b512, float* __restrict__ bp,
                       unsigned* __restrict__ cnt, unsigned* __restrict__ hist,
                       SelState* st) {
  int i = blockIdx.x * blockDim.x + threadIdx.x;
  if (i < NCOL * IC) {
    int col = i >> 7, k = i & 127;
    float v;
    if (col < 512) {
      int t = col >> 4, c = col & 15;
      v = inc_w[k * 1024 + t * 32 + c];
    } else {
      int t = col - 512;
      float a = 0.f;
      for (int j = 0; j < 16; ++j) a += inc_w[k * 1024 + t * 32 + 16 + j] * p_t[t * 16 + j];
      v = a;
    }
    Wf[col * IC + k] = v;
    return;
  }
  i -= NCOL * IC;
  if (i < OC * IC) { int c = i >> 7, k = i & 127; Wvt[c * IC + k] = lin_w[k * OC + c]; return; }
  i -= OC * IC;
  if (i < 512) { int t = i >> 4, c = i & 15; b512[i] = inc_b[t * 32 + c]; return; }
  i -= 512;
  if (i < 32) {
    float a = 0.f;
    for (int j = 0; j < 16; ++j) a += inc_b[i * 32 + 16 + j] * p_t[i * 16 + j];
    bp[i] = a;
    return;
  }
  i -= 32;
  if (i < NN) { cnt[i] = 0u; return; }
  i -= NN;
  if (i < 2048) { hist[i] = 0u; return; }
  i -= 2048;
  if (i == 0) {
    st->prefix = 0ull; st->r = KSEL; st->selc = 0u;
    for (int p = 0; p < 8; ++p) st->done[p] = 0u;
  }
}

// ------------------------------------------------- per-node GEMM + beta + V
__global__ __launch_bounds__(256) void k_node(
    const float* __restrict__ x, const float* __restrict__ mw,
    const float* __restrict__ Wf, const float* __restrict__ Wvt,
    const float* __restrict__ b512, const float* __restrict__ bp,
    const float* __restrict__ lin_b,
    float* __restrict__ beta, double* __restrict__ s64, float* __restrict__ V) {
  __shared__ float  xl32[NPB][IC];
  __shared__ double xl64[NPB][IC];
  __shared__ float  mwl[NPB][16];
  __shared__ double yl[NPB][NCOL];
  __shared__ double betad[NPB][NSTEP];
  int tid = threadIdx.x;
  int n0 = blockIdx.x * NPB;

  for (int i = tid; i < NPB * IC; i += 256) {
    int j = i >> 7, k = i & 127;
    float v = x[(n0 + j) * IC + k];
    xl32[j][k] = v; xl64[j][k] = (double)v;
  }
  for (int i = tid; i < NPB * 16; i += 256)
    mwl[i >> 4][i & 15] = mw[(n0 + (i >> 4)) * 16 + (i & 15)];
  __syncthreads();

  for (int col = tid; col < TOTCOL; col += 256) {
    if (col < NCOL) {
      const float* wc = Wf + col * IC;
      double a[NPB];
#pragma unroll
      for (int j = 0; j < NPB; ++j) a[j] = 0.0;
      for (int k = 0; k < IC; ++k) {
        double wv = (double)wc[k];
#pragma unroll
        for (int j = 0; j < NPB; ++j) a[j] = fma(wv, xl64[j][k], a[j]);
      }
#pragma unroll
      for (int j = 0; j < NPB; ++j) yl[j][col] = a[j];
    } else {
      int c = col - NCOL;
      const float* wc = Wvt + c * IC;
      float a[NPB];
#pragma unroll
      for (int j = 0; j < NPB; ++j) a[j] = 0.f;
      for (int k = 0; k < IC; ++k) {
        float wv = wc[k];
#pragma unroll
        for (int j = 0; j < NPB; ++j) a[j] = fmaf(wv, xl32[j][k], a[j]);
      }
      float b = lin_b[c];
#pragma unroll
      for (int j = 0; j < NPB; ++j) {
        float r = a[j] + b;
        V[(n0 + j) * OC + c] = r > 0.f ? r : 0.f;
      }
    }
  }
  __syncthreads();

  { // 256 threads = 8 nodes x 32 timesteps
    int j = tid >> 5, t = tid & 31;
    double bacc = yl[j][512 + t] + (double)bp[t];
    for (int c = 0; c < 16; ++c)
      bacc += (yl[j][t * 16 + c] + (double)b512[t * 16 + c]) * (double)mwl[j][c];
    bacc *= (1.0 / 32.0);
    beta[(n0 + j) * NSTEP + t] = (float)bacc;
    betad[j][t] = bacc;
  }
  __syncthreads();
  if (tid < NPB) {
    double s = 0.0;
    for (int t = 0; t < NSTEP; ++t) s += betad[tid][t];
    s64[n0 + tid] = s * (1.0 / 32.0);
  }
}

// ---------------------------------------------------------------- edge keys
__global__ void k_key(const int* __restrict__ ei, const float* __restrict__ ew,
                      const double* __restrict__ s64, unsigned long long* __restrict__ keys) {
  int e = blockIdx.x * 256 + threadIdx.x;
  if (e >= NE) return;
  int d = ei[NE + e];
  double v = s64[d] * (double)ew[e];
  unsigned long long u = (unsigned long long)__double_as_longlong(v);
  u = (u & 0x8000000000000000ull) ? ~u : (u | 0x8000000000000000ull);
  keys[e] = u;
}

// -------------------------------------------- radix select pass (hist+pick)
__global__ void k_radix(const unsigned long long* __restrict__ keys,
                        unsigned* __restrict__ hist, SelState* st, int p) {
  __shared__ unsigned h[256];
  __shared__ int last;
  int tid = threadIdx.x;
  h[tid] = 0u;
  if (tid == 0) last = 0;
  unsigned long long pref = (p == 0) ? 0ull : st->prefix;
  __syncthreads();
  int shift = 56 - 8 * p;
  unsigned* hp = hist + p * 256;
  for (int e = blockIdx.x * 256 + tid; e < NE; e += gridDim.x * 256) {
    unsigned long long k = keys[e];
    if (p == 0 || (k >> (shift + 8)) == pref)
      atomicAdd(&h[(unsigned)((k >> shift) & 255ull)], 1u);
  }
  __syncthreads();
  if (h[tid]) atomicAdd(&hp[tid], h[tid]);
  __threadfence();
  __syncthreads();
  if (tid == 0) {
    unsigned old = atomicAdd(&st->done[p], 1u);
    if (old == gridDim.x - 1) last = 1;
  }
  __syncthreads();
  if (last && tid == 0) {
    unsigned r = st->r;
    unsigned long long pr = st->prefix;
    int chosen = 0;
    for (int b = 255; b >= 0; --b) {
      unsigned c = atomicAdd(&hp[b], 0u);
      if (c < r) { r -= c; }
      else { chosen = b; break; }
    }
    st->prefix = (pr << 8) | (unsigned long long)chosen;
    st->r = r;
  }
}

// ------------------------------------------------------- selection + counts
__global__ void k_compact(const unsigned long long* __restrict__ keys,
                          const int* __restrict__ ei, SelState* st,
                          int* __restrict__ sel, unsigned* __restrict__ cnt) {
  int e = blockIdx.x * 256 + threadIdx.x;
  if (e >= NE) return;
  unsigned long long T = st->prefix;
  if (keys[e] > T) {
    unsigned pos = atomicAdd(&st->selc, 1u);
    sel[pos] = e;
    atomicAdd(&cnt[ei[e]], 1u);
  }
}

__global__ void k_tie(const unsigned long long* __restrict__ keys,
                      const int* __restrict__ ei, SelState* st,
                      int* __restrict__ sel, unsigned* __restrict__ cnt) {
  __shared__ unsigned sc[256];
  __shared__ unsigned staken;
  int tid = threadIdx.x;
  unsigned long long T = st->prefix;
  unsigned needed = st->r;
  if (tid == 0) staken = 0u;
  __syncthreads();
  for (int base = 0; base < NE; base += 256) {
    int e = base + tid;
    unsigned f = (e < NE && keys[e] == T) ? 1u : 0u;
    sc[tid] = f;
    __syncthreads();
    for (int s = 1; s < 256; s <<= 1) {
      unsigned v = (tid >= s) ? sc[tid - s] : 0u;
      __syncthreads();
      sc[tid] += v;
      __syncthreads();
    }
    unsigned incl = sc[tid];
    unsigned excl = incl - f;
    unsigned tk = staken;
    if (f && tk + excl < needed) {
      unsigned pos = atomicAdd(&st->selc, 1u);
      sel[pos] = e;
      atomicAdd(&cnt[ei[e]], 1u);
    }
    __syncthreads();
    if (tid == 0) staken += sc[255];
    __syncthreads();
    if (staken >= needed) break;
  }
}

// ------------------------------------------------------- prefix sum -> CSR
__global__ void k_prefix(const unsigned* __restrict__ cnt,
                         unsigned* __restrict__ offar, unsigned* __restrict__ cursor) {
  __shared__ unsigned sd[1024];
  __shared__ unsigned carry;
  int tid = threadIdx.x;
  if (tid == 0) carry = 0u;
  __syncthreads();
  for (int base = 0; base < NN; base += 1024) {
    int i = base + tid;
    unsigned v = (i < NN) ? cnt[i] : 0u;
    sd[tid] = v;
    __syncthreads();
    for (int s = 1; s < 1024; s <<= 1) {
      unsigned u = (tid >= s) ? sd[tid - s] : 0u;
      __syncthreads();
      sd[tid] += u;
      __syncthreads();
    }
    unsigned excl = carry + sd[tid] - v;
    if (i < NN) { offar[i] = excl; cursor[i] = excl; }
    __syncthreads();
    if (tid == 0) carry += sd[1023];
    __syncthreads();
  }
  if (tid == 0) offar[NN] = carry;
}

__global__ void k_scatter(const int* __restrict__ sel, const int* __restrict__ ei,
                          unsigned* __restrict__ cursor, int* __restrict__ csr) {
  int i = blockIdx.x * 256 + threadIdx.x;
  if (i >= KSEL) return;
  int e = sel[i];
  unsigned pos = atomicAdd(&cursor[ei[e]], 1u);
  csr[pos] = e;
}

// ------------------------------------- per-node softmax + weighted scatter
__global__ __launch_bounds__(128) void k_out(
    const int* __restrict__ ei, const float* __restrict__ ew,
    const float* __restrict__ beta, const float* __restrict__ V,
    const unsigned* __restrict__ offar, const int* __restrict__ csr,
    float* __restrict__ out) {
  __shared__ float m[NSTEP], den[NSTEP];
  __shared__ float g[32][NSTEP];
  __shared__ int dl[32];
  __shared__ float ewl[32];
  int n = blockIdx.x, tid = threadIdx.x;
  unsigned beg = offar[n], end = offar[n + 1];
  if (tid < NSTEP) {
    float mm = -INFINITY;
    for (unsigned i = beg; i < end; ++i) {
      int e = csr[i]; int d = ei[NE + e];
      float v = beta[d * NSTEP + tid] * ew[e];
      mm = fmaxf(mm, v);
    }
    m[tid] = mm;
    float dd = 0.f;
    for (unsigned i = beg; i < end; ++i) {
      int e = csr[i]; int d = ei[NE + e];
      float v = beta[d * NSTEP + tid] * ew[e];
      dd += expf(v - mm);
    }
    den[tid] = dd;
  }
  __syncthreads();
  float acc = 0.f;
  int c = tid, tq = tid >> 2;
  for (unsigned cb = beg; cb < end; cb += 32u) {
    unsigned ce = end - cb; if (ce > 32u) ce = 32u;
    if (tid < (int)ce) {
      int e = csr[cb + tid];
      dl[tid] = ei[NE + e];
      ewl[tid] = ew[e];
    }
    __syncthreads();
    for (int idx = tid; idx < (int)ce * NSTEP; idx += 128) {
      int el = idx >> 5, t = idx & 31;
      float v = beta[dl[el] * NSTEP + t] * ewl[el];
      g[el][t] = expf(v - m[t]) / den[t];
    }
    __syncthreads();
    for (int el = 0; el < (int)ce; ++el)
      acc += V[dl[el] * OC + c] * g[el][tq];
    __syncthreads();
  }
  out[n * OC + c] = acc;
}

// --------------------------------------------------------------------- host
extern "C" void kernel_launch(void* const* d_in, const int* in_sizes, int n_in,
                              void* d_out, int out_size, void* d_ws, size_t ws_size,
                              hipStream_t stream) {
  const float* x     = (const float*)d_in[0];
  const float* p_t   = (const float*)d_in[1];
  const int*   ei    = (const int*)d_in[2];
  const float* ew    = (const float*)d_in[3];
  const float* lin_w = (const float*)d_in[4];
  const float* lin_b = (const float*)d_in[5];
  const float* inc_w = (const float*)d_in[6];
  const float* inc_b = (const float*)d_in[7];
  const float* mw    = (const float*)d_in[8];
  float* out = (float*)d_out;

  char* w = (char*)d_ws;
  size_t off = 0;
  auto alloc = [&](size_t b) -> void* {
    void* p = w + off;
    off += (b + 511) & ~(size_t)511;
    return p;
  };
  float*  Wf    = (float*)alloc((size_t)NCOL * IC * 4);
  float*  Wvt   = (float*)alloc((size_t)OC * IC * 4);
  float*  b512  = (float*)alloc(512 * 4);
  float*  bp    = (float*)alloc(32 * 4);
  float*  beta  = (float*)alloc((size_t)NN * NSTEP * 4);
  double* s64   = (double*)alloc((size_t)NN * 8);
  float*  V     = (float*)alloc((size_t)NN * OC * 4);
  unsigned long long* keys = (unsigned long long*)alloc((size_t)NE * 8);
  int*      sel    = (int*)alloc((size_t)KSEL * 4);
  unsigned* cnt    = (unsigned*)alloc((size_t)NN * 4);
  unsigned* offar  = (unsigned*)alloc((size_t)(NN + 1) * 4);
  unsigned* cursor = (unsigned*)alloc((size_t)NN * 4);
  int*      csr    = (int*)alloc((size_t)KSEL * 4);
  unsigned* hist   = (unsigned*)alloc(8 * 256 * 4);
  SelState* st     = (SelState*)alloc(sizeof(SelState));
  if (off > ws_size) return;  // insufficient workspace

  int init_threads = NCOL * IC + OC * IC + 512 + 32 + NN + 2048 + 1;
  k_init<<<(init_threads + 255) / 256, 256, 0, stream>>>(p_t, lin_w, inc_w, inc_b,
                                                         Wf, Wvt, b512, bp, cnt, hist, st);
  k_node<<<NN / NPB, 256, 0, stream>>>(x, mw, Wf, Wvt, b512, bp, lin_b, beta, s64, V);
  k_key<<<(NE + 255) / 256, 256, 0, stream>>>(ei, ew, s64, keys);
  for (int p = 0; p < 8; ++p)
    k_radix<<<256, 256, 0, stream>>>(keys, hist, st, p);
  k_compact<<<(NE + 255) / 256, 256, 0, stream>>>(keys, ei, st, sel, cnt);
  k_tie<<<1, 256, 0, stream>>>(keys, ei, st, sel, cnt);
  k_prefix<<<1, 1024, 0, stream>>>(cnt, offar, cursor);
  k_scatter<<<(KSEL + 255) / 256, 256, 0, stream>>>(sel, ei, cursor, csr);
  k_out<<<NN, 128, 0, stream>>>(ei, ew, beta, V, offar, csr, out);
}

// Round 2
// 615.141 us; speedup vs baseline: 2.5809x; 2.5809x over previous
//
#include <hip/hip_runtime.h>

#define NN 20000
#define IC 128
#define OC 128
#define NSTEP 32
#define NE 256000
#define KSEL 128000
#define NCOL 544    // 512 w_v-path cols (t*16+c) + 32 p_t-folded cols
#define TOTCOL 672  // + 128 V cols
#define NPB 8       // nodes per block in k_node
#define TIECAP 65536

struct SelState {
  unsigned long long prefix;
  unsigned r;       // remaining rank; after pass 7 == "needed" among equals
  unsigned selc;    // selected count
  unsigned tiec;    // tie count
  unsigned done[8]; // per-pass block-done counters
};

// ---------------------------------------------------------------- init / fold
__global__ void k_init(const float* __restrict__ p_t, const float* __restrict__ lin_w,
                       const float* __restrict__ inc_w, const float* __restrict__ inc_b,
                       float* __restrict__ Wf, float* __restrict__ Wvt,
                       float* __restrict__ b512, float* __restrict__ bp,
                       unsigned* __restrict__ cnt, unsigned* __restrict__ hist,
                       SelState* st) {
  int i = blockIdx.x * blockDim.x + threadIdx.x;
  if (i < NCOL * IC) {
    int col = i >> 7, k = i & 127;
    float v;
    if (col < 512) {
      int t = col >> 4, c = col & 15;
      v = inc_w[k * 1024 + t * 32 + c];
    } else {
      int t = col - 512;
      float a = 0.f;
      for (int j = 0; j < 16; ++j) a += inc_w[k * 1024 + t * 32 + 16 + j] * p_t[t * 16 + j];
      v = a;
    }
    Wf[col * IC + k] = v;
    return;
  }
  i -= NCOL * IC;
  if (i < OC * IC) { int c = i >> 7, k = i & 127; Wvt[c * IC + k] = lin_w[k * OC + c]; return; }
  i -= OC * IC;
  if (i < 512) { int t = i >> 4, c = i & 15; b512[i] = inc_b[t * 32 + c]; return; }
  i -= 512;
  if (i < 32) {
    float a = 0.f;
    for (int j = 0; j < 16; ++j) a += inc_b[i * 32 + 16 + j] * p_t[i * 16 + j];
    bp[i] = a;
    return;
  }
  i -= 32;
  if (i < NN) { cnt[i] = 0u; return; }
  i -= NN;
  if (i < 2048) { hist[i] = 0u; return; }
  i -= 2048;
  if (i == 0) {
    st->prefix = 0ull; st->r = KSEL; st->selc = 0u; st->tiec = 0u;
    for (int p = 0; p < 8; ++p) st->done[p] = 0u;
  }
}

// ------------------------------------------------- per-node GEMM + beta + V
__global__ __launch_bounds__(256) void k_node(
    const float* __restrict__ x, const float* __restrict__ mw,
    const float* __restrict__ Wf, const float* __restrict__ Wvt,
    const float* __restrict__ b512, const float* __restrict__ bp,
    const float* __restrict__ lin_b,
    float* __restrict__ beta, double* __restrict__ s64, float* __restrict__ V) {
  __shared__ float  xl32[NPB][IC];
  __shared__ double xl64[NPB][IC];
  __shared__ float  mwl[NPB][16];
  __shared__ double yl[NPB][NCOL];
  __shared__ double betad[NPB][NSTEP];
  int tid = threadIdx.x;
  int n0 = blockIdx.x * NPB;

  for (int i = tid; i < NPB * IC; i += 256) {
    int j = i >> 7, k = i & 127;
    float v = x[(n0 + j) * IC + k];
    xl32[j][k] = v; xl64[j][k] = (double)v;
  }
  for (int i = tid; i < NPB * 16; i += 256)
    mwl[i >> 4][i & 15] = mw[(n0 + (i >> 4)) * 16 + (i & 15)];
  __syncthreads();

  for (int col = tid; col < TOTCOL; col += 256) {
    if (col < NCOL) {
      const float* wc = Wf + col * IC;
      double a[NPB];
#pragma unroll
      for (int j = 0; j < NPB; ++j) a[j] = 0.0;
      for (int k = 0; k < IC; ++k) {
        double wv = (double)wc[k];
#pragma unroll
        for (int j = 0; j < NPB; ++j) a[j] = fma(wv, xl64[j][k], a[j]);
      }
#pragma unroll
      for (int j = 0; j < NPB; ++j) yl[j][col] = a[j];
    } else {
      int c = col - NCOL;
      const float* wc = Wvt + c * IC;
      float a[NPB];
#pragma unroll
      for (int j = 0; j < NPB; ++j) a[j] = 0.f;
      for (int k = 0; k < IC; ++k) {
        float wv = wc[k];
#pragma unroll
        for (int j = 0; j < NPB; ++j) a[j] = fmaf(wv, xl32[j][k], a[j]);
      }
      float b = lin_b[c];
#pragma unroll
      for (int j = 0; j < NPB; ++j) {
        float r = a[j] + b;
        V[(n0 + j) * OC + c] = r > 0.f ? r : 0.f;
      }
    }
  }
  __syncthreads();

  { // 256 threads = 8 nodes x 32 timesteps
    int j = tid >> 5, t = tid & 31;
    double bacc = yl[j][512 + t] + (double)bp[t];
    for (int c = 0; c < 16; ++c)
      bacc += (yl[j][t * 16 + c] + (double)b512[t * 16 + c]) * (double)mwl[j][c];
    bacc *= (1.0 / 32.0);
    beta[(n0 + j) * NSTEP + t] = (float)bacc;
    betad[j][t] = bacc;
  }
  __syncthreads();
  if (tid < NPB) {
    double s = 0.0;
    for (int t = 0; t < NSTEP; ++t) s += betad[tid][t];
    s64[n0 + tid] = s * (1.0 / 32.0);
  }
}

// ---------------------------------------------------------------- edge keys
__global__ void k_key(const int* __restrict__ ei, const float* __restrict__ ew,
                      const double* __restrict__ s64, unsigned long long* __restrict__ keys) {
  int e = blockIdx.x * 256 + threadIdx.x;
  if (e >= NE) return;
  int d = ei[NE + e];
  double v = s64[d] * (double)ew[e];
  unsigned long long u = (unsigned long long)__double_as_longlong(v);
  u = (u & 0x8000000000000000ull) ? ~u : (u | 0x8000000000000000ull);
  keys[e] = u;
}

// -------------------------------------------- radix select pass (hist+pick)
__global__ void k_radix(const unsigned long long* __restrict__ keys,
                        unsigned* __restrict__ hist, SelState* st, int p) {
  __shared__ unsigned h[256];
  __shared__ int last;
  int tid = threadIdx.x;
  h[tid] = 0u;
  if (tid == 0) last = 0;
  unsigned long long pref = (p == 0) ? 0ull : st->prefix;
  __syncthreads();
  int shift = 56 - 8 * p;
  unsigned* hp = hist + p * 256;
  for (int e = blockIdx.x * 256 + tid; e < NE; e += gridDim.x * 256) {
    unsigned long long k = keys[e];
    if (p == 0 || (k >> (shift + 8)) == pref)
      atomicAdd(&h[(unsigned)((k >> shift) & 255ull)], 1u);
  }
  __syncthreads();
  if (h[tid]) atomicAdd(&hp[tid], h[tid]);
  __threadfence();
  __syncthreads();
  if (tid == 0) {
    unsigned old = atomicAdd(&st->done[p], 1u);
    if (old == gridDim.x - 1) last = 1;
  }
  __syncthreads();
  if (last && tid == 0) {
    unsigned r = st->r;
    unsigned long long pr = st->prefix;
    int chosen = 0;
    for (int b = 255; b >= 0; --b) {
      unsigned c = atomicAdd(&hp[b], 0u);
      if (c < r) { r -= c; }
      else { chosen = b; break; }
    }
    st->prefix = (pr << 8) | (unsigned long long)chosen;
    st->r = r;
  }
}

// ------------------------------------------------------- selection + counts
__global__ void k_compact(const unsigned long long* __restrict__ keys,
                          const int* __restrict__ ei, SelState* st,
                          int* __restrict__ sel, unsigned* __restrict__ cnt) {
  int e = blockIdx.x * 256 + threadIdx.x;
  if (e >= NE) return;
  unsigned long long T = st->prefix;
  if (keys[e] > T) {
    unsigned pos = atomicAdd(&st->selc, 1u);
    sel[pos] = e;
    atomicAdd(&cnt[ei[e]], 1u);
  }
}

// ---------------- parallel tie resolution: collect, then pick lowest indices
__global__ void k_tiecollect(const unsigned long long* __restrict__ keys,
                             SelState* st, int* __restrict__ tiebuf) {
  unsigned long long T = st->prefix;
  for (int e = blockIdx.x * 256 + threadIdx.x; e < NE; e += gridDim.x * 256) {
    if (keys[e] == T) {
      unsigned pos = atomicAdd(&st->tiec, 1u);
      if (pos < TIECAP) tiebuf[pos] = e;
    }
  }
}

__global__ void k_tiepick(const int* __restrict__ tiebuf, const int* __restrict__ ei,
                          SelState* st, int* __restrict__ sel, unsigned* __restrict__ cnt) {
  int tid = threadIdx.x;
  unsigned C = st->tiec; if (C > TIECAP) C = TIECAP;
  unsigned needed = st->r;
  if (C <= needed) {
    for (unsigned i = tid; i < C; i += 256) {
      int e = tiebuf[i];
      unsigned pos = atomicAdd(&st->selc, 1u);
      sel[pos] = e;
      atomicAdd(&cnt[ei[e]], 1u);
    }
    return;
  }
  for (unsigned i = tid; i < C; i += 256) {
    int e = tiebuf[i];
    unsigned rank = 0;
    for (unsigned j = 0; j < C; ++j) rank += (tiebuf[j] < e) ? 1u : 0u;
    if (rank < needed) {
      unsigned pos = atomicAdd(&st->selc, 1u);
      sel[pos] = e;
      atomicAdd(&cnt[ei[e]], 1u);
    }
  }
}

// ------------------------------------------------------- prefix sum -> CSR
__global__ void k_prefix(const unsigned* __restrict__ cnt,
                         unsigned* __restrict__ offar, unsigned* __restrict__ cursor) {
  __shared__ unsigned sd[1024];
  __shared__ unsigned carry;
  int tid = threadIdx.x;
  if (tid == 0) carry = 0u;
  __syncthreads();
  for (int base = 0; base < NN; base += 1024) {
    int i = base + tid;
    unsigned v = (i < NN) ? cnt[i] : 0u;
    sd[tid] = v;
    __syncthreads();
    for (int s = 1; s < 1024; s <<= 1) {
      unsigned u = (tid >= s) ? sd[tid - s] : 0u;
      __syncthreads();
      sd[tid] += u;
      __syncthreads();
    }
    unsigned excl = carry + sd[tid] - v;
    if (i < NN) { offar[i] = excl; cursor[i] = excl; }
    __syncthreads();
    if (tid == 0) carry += sd[1023];
    __syncthreads();
  }
  if (tid == 0) offar[NN] = carry;
}

__global__ void k_scatter(const int* __restrict__ sel, const int* __restrict__ ei,
                          unsigned* __restrict__ cursor, int* __restrict__ csr) {
  int i = blockIdx.x * 256 + threadIdx.x;
  if (i >= KSEL) return;
  int e = sel[i];
  unsigned pos = atomicAdd(&cursor[ei[e]], 1u);
  csr[pos] = e;
}

// ------------------------------------- per-node softmax + weighted scatter
__global__ __launch_bounds__(128) void k_out(
    const int* __restrict__ ei, const float* __restrict__ ew,
    const float* __restrict__ beta, const float* __restrict__ V,
    const unsigned* __restrict__ offar, const int* __restrict__ csr,
    float* __restrict__ out) {
  __shared__ float m[NSTEP], den[NSTEP];
  __shared__ float g[32][NSTEP];
  __shared__ int dl[32];
  __shared__ float ewl[32];
  int n = blockIdx.x, tid = threadIdx.x;
  unsigned beg = offar[n], end = offar[n + 1];
  if (tid < NSTEP) {
    float mm = -INFINITY;
    for (unsigned i = beg; i < end; ++i) {
      int e = csr[i]; int d = ei[NE + e];
      float v = beta[d * NSTEP + tid] * ew[e];
      mm = fmaxf(mm, v);
    }
    m[tid] = mm;
    float dd = 0.f;
    for (unsigned i = beg; i < end; ++i) {
      int e = csr[i]; int d = ei[NE + e];
      float v = beta[d * NSTEP + tid] * ew[e];
      dd += expf(v - mm);
    }
    den[tid] = dd;
  }
  __syncthreads();
  float acc = 0.f;
  int c = tid, tq = tid >> 2;
  for (unsigned cb = beg; cb < end; cb += 32u) {
    unsigned ce = end - cb; if (ce > 32u) ce = 32u;
    if (tid < (int)ce) {
      int e = csr[cb + tid];
      dl[tid] = ei[NE + e];
      ewl[tid] = ew[e];
    }
    __syncthreads();
    for (int idx = tid; idx < (int)ce * NSTEP; idx += 128) {
      int el = idx >> 5, t = idx & 31;
      float v = beta[dl[el] * NSTEP + t] * ewl[el];
      g[el][t] = expf(v - m[t]) / den[t];
    }
    __syncthreads();
    for (int el = 0; el < (int)ce; ++el)
      acc += V[dl[el] * OC + c] * g[el][tq];
    __syncthreads();
  }
  out[n * OC + c] = acc;
}

// --------------------------------------------------------------------- host
extern "C" void kernel_launch(void* const* d_in, const int* in_sizes, int n_in,
                              void* d_out, int out_size, void* d_ws, size_t ws_size,
                              hipStream_t stream) {
  const float* x     = (const float*)d_in[0];
  const float* p_t   = (const float*)d_in[1];
  const int*   ei    = (const int*)d_in[2];
  const float* ew    = (const float*)d_in[3];
  const float* lin_w = (const float*)d_in[4];
  const float* lin_b = (const float*)d_in[5];
  const float* inc_w = (const float*)d_in[6];
  const float* inc_b = (const float*)d_in[7];
  const float* mw    = (const float*)d_in[8];
  float* out = (float*)d_out;

  char* w = (char*)d_ws;
  size_t off = 0;
  auto alloc = [&](size_t b) -> void* {
    void* p = w + off;
    off += (b + 511) & ~(size_t)511;
    return p;
  };
  float*  Wf    = (float*)alloc((size_t)NCOL * IC * 4);
  float*  Wvt   = (float*)alloc((size_t)OC * IC * 4);
  float*  b512  = (float*)alloc(512 * 4);
  float*  bp    = (float*)alloc(32 * 4);
  float*  beta  = (float*)alloc((size_t)NN * NSTEP * 4);
  double* s64   = (double*)alloc((size_t)NN * 8);
  float*  V     = (float*)alloc((size_t)NN * OC * 4);
  unsigned long long* keys = (unsigned long long*)alloc((size_t)NE * 8);
  int*      sel    = (int*)alloc((size_t)KSEL * 4);
  unsigned* cnt    = (unsigned*)alloc((size_t)NN * 4);
  unsigned* offar  = (unsigned*)alloc((size_t)(NN + 1) * 4);
  unsigned* cursor = (unsigned*)alloc((size_t)NN * 4);
  int*      csr    = (int*)alloc((size_t)KSEL * 4);
  unsigned* hist   = (unsigned*)alloc(8 * 256 * 4);
  int*      tiebuf = (int*)alloc((size_t)TIECAP * 4);
  SelState* st     = (SelState*)alloc(sizeof(SelState));
  if (off > ws_size) return;  // insufficient workspace

  int init_threads = NCOL * IC + OC * IC + 512 + 32 + NN + 2048 + 1;
  k_init<<<(init_threads + 255) / 256, 256, 0, stream>>>(p_t, lin_w, inc_w, inc_b,
                                                         Wf, Wvt, b512, bp, cnt, hist, st);
  k_node<<<NN / NPB, 256, 0, stream>>>(x, mw, Wf, Wvt, b512, bp, lin_b, beta, s64, V);
  k_key<<<(NE + 255) / 256, 256, 0, stream>>>(ei, ew, s64, keys);
  for (int p = 0; p < 8; ++p)
    k_radix<<<256, 256, 0, stream>>>(keys, hist, st, p);
  k_compact<<<(NE + 255) / 256, 256, 0, stream>>>(keys, ei, st, sel, cnt);
  k_tiecollect<<<256, 256, 0, stream>>>(keys, st, tiebuf);
  k_tiepick<<<1, 256, 0, stream>>>(tiebuf, ei, st, sel, cnt);
  k_prefix<<<1, 1024, 0, stream>>>(cnt, offar, cursor);
  k_scatter<<<(KSEL + 255) / 256, 256, 0, stream>>>(sel, ei, cursor, csr);
  k_out<<<NN, 128, 0, stream>>>(ei, ew, beta, V, offar, csr, out);
}

// Round 3
// 506.624 us; speedup vs baseline: 3.1337x; 1.2142x over previous
//
#include <hip/hip_runtime.h>

#define NN 20000
#define IC 128
#define OC 128
#define NSTEP 32
#define NE 256000
#define KSEL 128000
#define NCOL 544    // 512 w_v-path cols (t*16+c) + 32 p_t-folded cols
#define TOTCOL 672  // + 128 V cols
#define NPB 8       // nodes per block in k_node
#define TIECAP 65536
#define NB 79       // prefix-scan blocks = ceil(NN/256)

struct SelState {
  unsigned long long prefix;
  unsigned r;       // remaining rank; after pass 7 == "needed" among equals
  unsigned selc;    // selected count
  unsigned tiec;    // tie count
  unsigned done[8]; // per-pass block-done counters
};

// ---------------------------------------------------------------- init / fold
__global__ void k_init(const float* __restrict__ p_t, const float* __restrict__ lin_w,
                       const float* __restrict__ inc_w, const float* __restrict__ inc_b,
                       float* __restrict__ Wf, float* __restrict__ Wvt,
                       float* __restrict__ b512, float* __restrict__ bp,
                       double* __restrict__ Ud, double* __restrict__ ubd,
                       unsigned* __restrict__ cnt, unsigned* __restrict__ hist,
                       SelState* st) {
  int i = blockIdx.x * blockDim.x + threadIdx.x;
  if (i < NCOL * IC) {
    int col = i >> 7, k = i & 127;
    float v;
    if (col < 512) {
      int t = col >> 4, c = col & 15;
      v = inc_w[k * 1024 + t * 32 + c];
    } else {
      int t = col - 512;
      float a = 0.f;
      for (int j = 0; j < 16; ++j) a += inc_w[k * 1024 + t * 32 + 16 + j] * p_t[t * 16 + j];
      v = a;
    }
    Wf[col * IC + k] = v;
    return;
  }
  i -= NCOL * IC;
  if (i < OC * IC) { int c = i >> 7, k = i & 127; Wvt[c * IC + k] = lin_w[k * OC + c]; return; }
  i -= OC * IC;
  if (i < 512) { int t = i >> 4, c = i & 15; b512[i] = inc_b[t * 32 + c]; return; }
  i -= 512;
  if (i < 32) {
    float a = 0.f;
    for (int j = 0; j < 16; ++j) a += inc_b[i * 32 + 16 + j] * p_t[i * 16 + j];
    bp[i] = a;
    return;
  }
  i -= 32;
  if (i < 17 * IC) {  // f64 folded selection columns: U (16) and q (1)
    int c = i >> 7, k = i & 127;
    double a = 0.0;
    if (c < 16) {
      for (int t = 0; t < NSTEP; ++t) a += (double)inc_w[k * 1024 + t * 32 + c];
    } else {
      for (int t = 0; t < NSTEP; ++t)
        for (int j = 0; j < 16; ++j)
          a += (double)inc_w[k * 1024 + t * 32 + 16 + j] * (double)p_t[t * 16 + j];
    }
    Ud[c * IC + k] = a;
    return;
  }
  i -= 17 * IC;
  if (i < 17) {
    double a = 0.0;
    if (i < 16) {
      for (int t = 0; t < NSTEP; ++t) a += (double)inc_b[t * 32 + i];
    } else {
      for (int t = 0; t < NSTEP; ++t)
        for (int j = 0; j < 16; ++j)
          a += (double)inc_b[t * 32 + 16 + j] * (double)p_t[t * 16 + j];
    }
    ubd[i] = a;
    return;
  }
  i -= 17;
  if (i < NN) { cnt[i] = 0u; return; }
  i -= NN;
  if (i < 2048) { hist[i] = 0u; return; }
  i -= 2048;
  if (i == 0) {
    st->prefix = 0ull; st->r = KSEL; st->selc = 0u; st->tiec = 0u;
    for (int p = 0; p < 8; ++p) st->done[p] = 0u;
  }
}

// --------------------- per-node: f32 GEMM (beta + V) + 17-col f64 s-keys
__global__ __launch_bounds__(256) void k_node(
    const float* __restrict__ x, const float* __restrict__ mw,
    const float* __restrict__ Wf, const float* __restrict__ Wvt,
    const float* __restrict__ b512, const float* __restrict__ bp,
    const float* __restrict__ lin_b, const double* __restrict__ Ud,
    const double* __restrict__ ubd,
    float* __restrict__ beta, double* __restrict__ s64, float* __restrict__ V) {
  __shared__ float xl[NPB][IC];
  __shared__ float mwl[NPB][16];
  __shared__ float yl[NPB][NCOL];
  __shared__ double sdd[NPB][17];
  int tid = threadIdx.x;
  int n0 = blockIdx.x * NPB;

  // vectorized staging: NPB*IC floats = 256 float4
  ((float4*)xl)[tid] = ((const float4*)(x + (size_t)n0 * IC))[tid];
  if (tid < NPB * 16 / 4) ((float4*)mwl)[tid] = ((const float4*)(mw + n0 * 16))[tid];
  __syncthreads();

  // f32 GEMM: 2 columns per thread so one xl b128 read feeds 8 FMAs
  for (int pc = tid; pc < TOTCOL / 2; pc += 256) {
    int c0 = pc * 2;
    if (c0 < NCOL) {
      const float4* w0 = (const float4*)(Wf + c0 * IC);
      const float4* w1 = (const float4*)(Wf + (c0 + 1) * IC);
      float a0[NPB], a1[NPB];
#pragma unroll
      for (int j = 0; j < NPB; ++j) { a0[j] = 0.f; a1[j] = 0.f; }
      for (int k4 = 0; k4 < IC / 4; ++k4) {
        float4 wa = w0[k4], wb = w1[k4];
#pragma unroll
        for (int j = 0; j < NPB; ++j) {
          float4 xv = ((const float4*)xl[j])[k4];
          a0[j] = fmaf(wa.x, xv.x, fmaf(wa.y, xv.y, fmaf(wa.z, xv.z, fmaf(wa.w, xv.w, a0[j]))));
          a1[j] = fmaf(wb.x, xv.x, fmaf(wb.y, xv.y, fmaf(wb.z, xv.z, fmaf(wb.w, xv.w, a1[j]))));
        }
      }
#pragma unroll
      for (int j = 0; j < NPB; ++j) { yl[j][c0] = a0[j]; yl[j][c0 + 1] = a1[j]; }
    } else {
      int v0 = c0 - NCOL;
      const float4* w0 = (const float4*)(Wvt + v0 * IC);
      const float4* w1 = (const float4*)(Wvt + (v0 + 1) * IC);
      float a0[NPB], a1[NPB];
#pragma unroll
      for (int j = 0; j < NPB; ++j) { a0[j] = 0.f; a1[j] = 0.f; }
      for (int k4 = 0; k4 < IC / 4; ++k4) {
        float4 wa = w0[k4], wb = w1[k4];
#pragma unroll
        for (int j = 0; j < NPB; ++j) {
          float4 xv = ((const float4*)xl[j])[k4];
          a0[j] = fmaf(wa.x, xv.x, fmaf(wa.y, xv.y, fmaf(wa.z, xv.z, fmaf(wa.w, xv.w, a0[j]))));
          a1[j] = fmaf(wb.x, xv.x, fmaf(wb.y, xv.y, fmaf(wb.z, xv.z, fmaf(wb.w, xv.w, a1[j]))));
        }
      }
      float bb0 = lin_b[v0], bb1 = lin_b[v0 + 1];
#pragma unroll
      for (int j = 0; j < NPB; ++j) {
        float r0 = a0[j] + bb0, r1 = a1[j] + bb1;
        V[(size_t)(n0 + j) * OC + v0]     = r0 > 0.f ? r0 : 0.f;
        V[(size_t)(n0 + j) * OC + v0 + 1] = r1 > 0.f ? r1 : 0.f;
      }
    }
  }

  // f64 selection dots: 17 folded columns per node (exact-selection path)
  if (tid < NPB * 17) {
    int j = tid / 17, c = tid - j * 17;
    const double* uc = Ud + c * IC;
    double a = 0.0;
    for (int k = 0; k < IC; ++k) a = fma(uc[k], (double)xl[j][k], a);
    sdd[j][c] = a;
  }
  __syncthreads();

  { // beta combine (f32): 256 threads = 8 nodes x 32 timesteps
    int j = tid >> 5, t = tid & 31;
    float bacc = yl[j][512 + t] + bp[t];
#pragma unroll
    for (int c = 0; c < 16; ++c)
      bacc = fmaf(yl[j][t * 16 + c] + b512[t * 16 + c], mwl[j][c], bacc);
    beta[(size_t)(n0 + j) * NSTEP + t] = bacc * (1.f / 32.f);
  }
  if (tid < NPB) {  // s combine (f64)
    double s = sdd[tid][16] + ubd[16];
    for (int c = 0; c < 16; ++c) s += (sdd[tid][c] + ubd[c]) * (double)mwl[tid][c];
    s64[n0 + tid] = s * (1.0 / 1024.0);
  }
}

// ---------------------------------------------------------------- edge keys
__global__ void k_key(const int* __restrict__ ei, const float* __restrict__ ew,
                      const double* __restrict__ s64, unsigned long long* __restrict__ keys) {
  int e = blockIdx.x * 256 + threadIdx.x;
  if (e >= NE) return;
  int d = ei[NE + e];
  double v = s64[d] * (double)ew[e];
  unsigned long long u = (unsigned long long)__double_as_longlong(v);
  u = (u & 0x8000000000000000ull) ? ~u : (u | 0x8000000000000000ull);
  keys[e] = u;
}

// ------------------- radix select pass (hist + parallel suffix-scan pick)
__global__ void k_radix(const unsigned long long* __restrict__ keys,
                        unsigned* __restrict__ hist, SelState* st, int p) {
  __shared__ unsigned h[256];
  __shared__ unsigned suf[256];
  __shared__ int last;
  int tid = threadIdx.x;
  h[tid] = 0u;
  if (tid == 0) last = 0;
  unsigned long long pref = (p == 0) ? 0ull : st->prefix;
  __syncthreads();
  int shift = 56 - 8 * p;
  unsigned* hp = hist + p * 256;
  for (int e = blockIdx.x * 256 + tid; e < NE; e += gridDim.x * 256) {
    unsigned long long k = keys[e];
    if (p == 0 || (k >> (shift + 8)) == pref)
      atomicAdd(&h[(unsigned)((k >> shift) & 255ull)], 1u);
  }
  __syncthreads();
  if (h[tid]) atomicAdd(&hp[tid], h[tid]);
  __threadfence();
  __syncthreads();
  if (tid == 0) {
    unsigned old = atomicAdd(&st->done[p], 1u);
    if (old == gridDim.x - 1) last = 1;
  }
  __syncthreads();
  if (!last) return;
  // last block: all bins finalized; parallel pick
  unsigned c = atomicAdd(&hp[tid], 0u);
  suf[tid] = c;
  __syncthreads();
  for (int d = 1; d < 256; d <<= 1) {
    unsigned v = (tid + d < 256) ? suf[tid + d] : 0u;
    __syncthreads();
    suf[tid] += v;
    __syncthreads();
  }
  unsigned r = st->r;
  unsigned exc = suf[tid] - c;       // count of keys in bins > tid (within prefix)
  if (exc < r && exc + c >= r) {     // r-th largest falls in bin tid
    st->prefix = (st->prefix << 8) | (unsigned long long)tid;
    st->r = r - exc;
  }
}

// --------------------------- selection (> T) + tie collection (== T), merged
__global__ void k_compact(const unsigned long long* __restrict__ keys,
                          const int* __restrict__ ei, SelState* st,
                          int* __restrict__ sel, unsigned* __restrict__ cnt,
                          int* __restrict__ tiebuf) {
  int e = blockIdx.x * 256 + threadIdx.x;
  if (e >= NE) return;
  unsigned long long k = keys[e], T = st->prefix;
  if (k > T) {
    unsigned pos = atomicAdd(&st->selc, 1u);
    sel[pos] = e;
    atomicAdd(&cnt[ei[e]], 1u);
  } else if (k == T) {
    unsigned pos = atomicAdd(&st->tiec, 1u);
    if (pos < TIECAP) tiebuf[pos] = e;
  }
}

__global__ void k_tiepick(const int* __restrict__ tiebuf, const int* __restrict__ ei,
                          SelState* st, int* __restrict__ sel, unsigned* __restrict__ cnt) {
  int tid = threadIdx.x;
  unsigned C = st->tiec; if (C > TIECAP) C = TIECAP;
  unsigned needed = st->r;
  if (C <= needed) {
    for (unsigned i = tid; i < C; i += 256) {
      int e = tiebuf[i];
      unsigned pos = atomicAdd(&st->selc, 1u);
      sel[pos] = e;
      atomicAdd(&cnt[ei[e]], 1u);
    }
    return;
  }
  for (unsigned i = tid; i < C; i += 256) {
    int e = tiebuf[i];
    unsigned rank = 0;
    for (unsigned j = 0; j < C; ++j) rank += (tiebuf[j] < e) ? 1u : 0u;
    if (rank < needed) {
      unsigned pos = atomicAdd(&st->selc, 1u);
      sel[pos] = e;
      atomicAdd(&cnt[ei[e]], 1u);
    }
  }
}

// ----------------------------------------------- 3-phase prefix sum -> CSR
__global__ void k_pref1(const unsigned* __restrict__ cnt, unsigned* __restrict__ bsum) {
  __shared__ unsigned sd[256];
  int i = blockIdx.x * 256 + threadIdx.x;
  sd[threadIdx.x] = (i < NN) ? cnt[i] : 0u;
  __syncthreads();
  for (int s = 128; s > 0; s >>= 1) {
    if (threadIdx.x < s) sd[threadIdx.x] += sd[threadIdx.x + s];
    __syncthreads();
  }
  if (threadIdx.x == 0) bsum[blockIdx.x] = sd[0];
}

__global__ void k_pref2(const unsigned* __restrict__ bsum, unsigned* __restrict__ bbase,
                        unsigned* __restrict__ offar) {
  __shared__ unsigned sd[128];
  int tid = threadIdx.x;
  unsigned v = (tid < NB) ? bsum[tid] : 0u;
  sd[tid] = v;
  __syncthreads();
  for (int d = 1; d < 128; d <<= 1) {
    unsigned u = (tid >= d) ? sd[tid - d] : 0u;
    __syncthreads();
    sd[tid] += u;
    __syncthreads();
  }
  if (tid < NB) bbase[tid] = sd[tid] - v;
  if (tid == NB - 1) offar[NN] = sd[tid];
}

__global__ void k_pref3(const unsigned* __restrict__ cnt, const unsigned* __restrict__ bbase,
                        unsigned* __restrict__ offar, unsigned* __restrict__ cursor) {
  __shared__ unsigned sd[256];
  int tid = threadIdx.x;
  int i = blockIdx.x * 256 + tid;
  unsigned v = (i < NN) ? cnt[i] : 0u;
  sd[tid] = v;
  __syncthreads();
  for (int d = 1; d < 256; d <<= 1) {
    unsigned u = (tid >= d) ? sd[tid - d] : 0u;
    __syncthreads();
    sd[tid] += u;
    __syncthreads();
  }
  if (i < NN) {
    unsigned excl = bbase[blockIdx.x] + sd[tid] - v;
    offar[i] = excl;
    cursor[i] = excl;
  }
}

__global__ void k_scatter(const int* __restrict__ sel, const int* __restrict__ ei,
                          unsigned* __restrict__ cursor, int* __restrict__ csr) {
  int i = blockIdx.x * 256 + threadIdx.x;
  if (i >= KSEL) return;
  int e = sel[i];
  unsigned pos = atomicAdd(&cursor[ei[e]], 1u);
  csr[pos] = e;
}

// ------------------------------------- per-node softmax + weighted scatter
__global__ __launch_bounds__(128) void k_out(
    const int* __restrict__ ei, const float* __restrict__ ew,
    const float* __restrict__ beta, const float* __restrict__ V,
    const unsigned* __restrict__ offar, const int* __restrict__ csr,
    float* __restrict__ out) {
  __shared__ float m[NSTEP], den[NSTEP];
  __shared__ float g[32][NSTEP];
  __shared__ int dl[32];
  __shared__ float ewl[32];
  int n = blockIdx.x, tid = threadIdx.x;
  unsigned beg = offar[n], end = offar[n + 1];
  if (tid < NSTEP) {
    float mm = -INFINITY;
    for (unsigned i = beg; i < end; ++i) {
      int e = csr[i]; int d = ei[NE + e];
      float v = beta[d * NSTEP + tid] * ew[e];
      mm = fmaxf(mm, v);
    }
    m[tid] = mm;
    float dd = 0.f;
    for (unsigned i = beg; i < end; ++i) {
      int e = csr[i]; int d = ei[NE + e];
      float v = beta[d * NSTEP + tid] * ew[e];
      dd += expf(v - mm);
    }
    den[tid] = dd;
  }
  __syncthreads();
  float acc = 0.f;
  int c = tid, tq = tid >> 2;
  for (unsigned cb = beg; cb < end; cb += 32u) {
    unsigned ce = end - cb; if (ce > 32u) ce = 32u;
    if (tid < (int)ce) {
      int e = csr[cb + tid];
      dl[tid] = ei[NE + e];
      ewl[tid] = ew[e];
    }
    __syncthreads();
    for (int idx = tid; idx < (int)ce * NSTEP; idx += 128) {
      int el = idx >> 5, t = idx & 31;
      float v = beta[dl[el] * NSTEP + t] * ewl[el];
      g[el][t] = expf(v - m[t]) / den[t];
    }
    __syncthreads();
    for (int el = 0; el < (int)ce; ++el)
      acc += V[dl[el] * OC + c] * g[el][tq];
    __syncthreads();
  }
  out[n * OC + c] = acc;
}

// --------------------------------------------------------------------- host
extern "C" void kernel_launch(void* const* d_in, const int* in_sizes, int n_in,
                              void* d_out, int out_size, void* d_ws, size_t ws_size,
                              hipStream_t stream) {
  const float* x     = (const float*)d_in[0];
  const float* p_t   = (const float*)d_in[1];
  const int*   ei    = (const int*)d_in[2];
  const float* ew    = (const float*)d_in[3];
  const float* lin_w = (const float*)d_in[4];
  const float* lin_b = (const float*)d_in[5];
  const float* inc_w = (const float*)d_in[6];
  const float* inc_b = (const float*)d_in[7];
  const float* mw    = (const float*)d_in[8];
  float* out = (float*)d_out;

  char* w = (char*)d_ws;
  size_t off = 0;
  auto alloc = [&](size_t b) -> void* {
    void* p = w + off;
    off += (b + 511) & ~(size_t)511;
    return p;
  };
  float*  Wf    = (float*)alloc((size_t)NCOL * IC * 4);
  float*  Wvt   = (float*)alloc((size_t)OC * IC * 4);
  float*  b512  = (float*)alloc(512 * 4);
  float*  bp    = (float*)alloc(32 * 4);
  double* Ud    = (double*)alloc((size_t)17 * IC * 8);
  double* ubd   = (double*)alloc(17 * 8);
  float*  beta  = (float*)alloc((size_t)NN * NSTEP * 4);
  double* s64   = (double*)alloc((size_t)NN * 8);
  float*  V     = (float*)alloc((size_t)NN * OC * 4);
  unsigned long long* keys = (unsigned long long*)alloc((size_t)NE * 8);
  int*      sel    = (int*)alloc((size_t)KSEL * 4);
  unsigned* cnt    = (unsigned*)alloc((size_t)NN * 4);
  unsigned* offar  = (unsigned*)alloc((size_t)(NN + 1) * 4);
  unsigned* cursor = (unsigned*)alloc((size_t)NN * 4);
  int*      csr    = (int*)alloc((size_t)KSEL * 4);
  unsigned* hist   = (unsigned*)alloc(8 * 256 * 4);
  int*      tiebuf = (int*)alloc((size_t)TIECAP * 4);
  unsigned* bsum   = (unsigned*)alloc(NB * 4);
  unsigned* bbase  = (unsigned*)alloc(NB * 4);
  SelState* st     = (SelState*)alloc(sizeof(SelState));
  if (off > ws_size) return;  // insufficient workspace

  int init_threads = NCOL * IC + OC * IC + 512 + 32 + 17 * IC + 17 + NN + 2048 + 1;
  k_init<<<(init_threads + 255) / 256, 256, 0, stream>>>(p_t, lin_w, inc_w, inc_b,
                                                         Wf, Wvt, b512, bp, Ud, ubd,
                                                         cnt, hist, st);
  k_node<<<NN / NPB, 256, 0, stream>>>(x, mw, Wf, Wvt, b512, bp, lin_b, Ud, ubd,
                                       beta, s64, V);
  k_key<<<(NE + 255) / 256, 256, 0, stream>>>(ei, ew, s64, keys);
  for (int p = 0; p < 8; ++p)
    k_radix<<<256, 256, 0, stream>>>(keys, hist, st, p);
  k_compact<<<(NE + 255) / 256, 256, 0, stream>>>(keys, ei, st, sel, cnt, tiebuf);
  k_tiepick<<<1, 256, 0, stream>>>(tiebuf, ei, st, sel, cnt);
  k_pref1<<<NB, 256, 0, stream>>>(cnt, bsum);
  k_pref2<<<1, 128, 0, stream>>>(bsum, bbase, offar);
  k_pref3<<<NB, 256, 0, stream>>>(cnt, bbase, offar, cursor);
  k_scatter<<<(KSEL + 255) / 256, 256, 0, stream>>>(sel, ei, cursor, csr);
  k_out<<<NN, 128, 0, stream>>>(ei, ew, beta, V, offar, csr, out);
}

// Round 5
// 421.664 us; speedup vs baseline: 3.7651x; 1.2015x over previous
//
#include <hip/hip_runtime.h>

#define NN 20000
#define IC 128
#define OC 128
#define NSTEP 32
#define NE 256000
#define KSEL 128000
#define NB 79        // prefix-scan blocks = ceil(NN/256)
#define CANDCAP 131072
#define NQCOL 704    // 512 beta + 32 p + 128 V + 32 pad

struct SelState {
  unsigned long long prefix;
  unsigned r;       // remaining rank
  unsigned selc;    // selected count
  unsigned tiec;    // candidate count
  unsigned done[8]; // block-done counters
};

typedef __attribute__((ext_vector_type(16))) float f16v;

// ---------------------------------------------------------------- init / fold
// Wq layout: float4 index = k4*NQCOL + col ; element jj = W[col][4*k4+jj]
// k4=0..31 weights; k4==32 = bias row (elements jj>0 are 0); cols 672..703 = 0
__global__ void k_init(const float* __restrict__ p_t, const float* __restrict__ lin_w,
                       const float* __restrict__ inc_w, const float* __restrict__ inc_b,
                       float* __restrict__ Wq,
                       double* __restrict__ Ud, double* __restrict__ ubd,
                       unsigned* __restrict__ cnt, unsigned* __restrict__ hist,
                       SelState* st) {
  int i = blockIdx.x * blockDim.x + threadIdx.x;
  if (i < 33 * NQCOL) {
    int k4 = i / NQCOL, col = i - k4 * NQCOL;
    float4 o;
    float* ov = (float*)&o;
    for (int jj = 0; jj < 4; ++jj) {
      int k = 4 * k4 + jj;
      float v = 0.f;
      if (col < 512) {
        int t = col >> 4, c = col & 15;
        if (k < 128) v = inc_w[k * 1024 + t * 32 + c];
        else if (k == 128) v = inc_b[t * 32 + c];
      } else if (col < 544) {
        int t = col - 512;
        if (k < 128) {
          float a = 0.f;
          for (int q = 0; q < 16; ++q) a += inc_w[k * 1024 + t * 32 + 16 + q] * p_t[t * 16 + q];
          v = a;
        } else if (k == 128) {
          float a = 0.f;
          for (int q = 0; q < 16; ++q) a += inc_b[t * 32 + 16 + q] * p_t[t * 16 + q];
          v = a;
        }
      } else if (col < 672) {
        int c = col - 544;
        if (k < 128) v = lin_w[k * OC + c];
        // k==128 (bias) patched by k_init2
      }
      ov[jj] = v;
    }
    ((float4*)Wq)[i] = o;
    return;
  }
  i -= 33 * NQCOL;
  if (i < 17 * IC) {  // f64 folded selection columns: U (16) and q (1)
    int c = i >> 7, k = i & 127;
    double a = 0.0;
    if (c < 16) {
      for (int t = 0; t < NSTEP; ++t) a += (double)inc_w[k * 1024 + t * 32 + c];
    } else {
      for (int t = 0; t < NSTEP; ++t)
        for (int q = 0; q < 16; ++q)
          a += (double)inc_w[k * 1024 + t * 32 + 16 + q] * (double)p_t[t * 16 + q];
    }
    Ud[c * IC + k] = a;
    return;
  }
  i -= 17 * IC;
  if (i < 17) {
    double a = 0.0;
    if (i < 16) {
      for (int t = 0; t < NSTEP; ++t) a += (double)inc_b[t * 32 + i];
    } else {
      for (int t = 0; t < NSTEP; ++t)
        for (int q = 0; q < 16; ++q)
          a += (double)inc_b[t * 32 + 16 + q] * (double)p_t[t * 16 + q];
    }
    ubd[i] = a;
    return;
  }
  i -= 17;
  if (i < NN) { cnt[i] = 0u; return; }
  i -= NN;
  if (i < 512) { hist[i] = 0u; return; }
  i -= 512;
  if (i == 0) {
    st->prefix = 0ull; st->r = KSEL; st->selc = 0u; st->tiec = 0u;
    for (int p = 0; p < 8; ++p) st->done[p] = 0u;
  }
}

// patch: bias row for V columns (k==128 -> k4==32, element 0)
__global__ void k_init2(const float* __restrict__ lin_b, float* __restrict__ Wq) {
  int c = threadIdx.x;  // 0..127
  Wq[((size_t)32 * NQCOL + 544 + c) * 4 + 0] = lin_b[c];
}

// ---------------- per-node GEMM: uniform weights, per-lane node rows
#define FMA4(WV, BASE)                                                                        \
  acc[BASE+0] = fmaf(xf.x, WV[0],  fmaf(xf.y, WV[1],  fmaf(xf.z, WV[2],  fmaf(xf.w, WV[3],  acc[BASE+0])))); \
  acc[BASE+1] = fmaf(xf.x, WV[4],  fmaf(xf.y, WV[5],  fmaf(xf.z, WV[6],  fmaf(xf.w, WV[7],  acc[BASE+1])))); \
  acc[BASE+2] = fmaf(xf.x, WV[8],  fmaf(xf.y, WV[9],  fmaf(xf.z, WV[10], fmaf(xf.w, WV[11], acc[BASE+2])))); \
  acc[BASE+3] = fmaf(xf.x, WV[12], fmaf(xf.y, WV[13], fmaf(xf.z, WV[14], fmaf(xf.w, WV[15], acc[BASE+3]))));

__global__ __launch_bounds__(256) void k_node(
    const float* __restrict__ x, const float* __restrict__ mw,
    const float* __restrict__ Wq, const double* __restrict__ Ud,
    const double* __restrict__ ubd,
    float* __restrict__ beta, double* __restrict__ s64, float* __restrict__ V) {
  __shared__ float4 xl[64 * 32];       // rotated: [m*32 + ((k4+m)&31)]
  __shared__ float betaAcc[64][33];
  __shared__ double sdd[64][17];
  int tid = threadIdx.x;
  int n0 = blockIdx.x * 64;
  int nvalid = NN - n0; if (nvalid > 64) nvalid = 64;

  for (int i = tid; i < 64 * 32; i += 256) {
    int mm = i >> 5, k4 = i & 31;
    float4 v = make_float4(0.f, 0.f, 0.f, 0.f);
    if (mm < nvalid) v = ((const float4*)(x + (size_t)(n0 + mm) * IC))[k4];
    xl[(mm << 5) + ((k4 + mm) & 31)] = v;
  }
  __syncthreads();

  // f64 selection dots (exact top-k path): 64 nodes x 17 cols
  for (int d = tid; d < 64 * 17; d += 256) {
    int m2 = d / 17, c = d - m2 * 17;
    const double* uc = Ud + c * IC;
    double a = 0.0;
    for (int k4 = 0; k4 < 32; ++k4) {
      float4 xv = xl[(m2 << 5) + ((k4 + m2) & 31)];
      a = fma((double)xv.x, uc[4 * k4], a);
      a = fma((double)xv.y, uc[4 * k4 + 1], a);
      a = fma((double)xv.z, uc[4 * k4 + 2], a);
      a = fma((double)xv.w, uc[4 * k4 + 3], a);
    }
    sdd[m2][c] = a;
  }

  int m = tid & 63;
  int j = __builtin_amdgcn_readfirstlane(threadIdx.x >> 6);  // wave id 0..3
  float mwr[16];
  {
    int mm = (m < nvalid) ? m : 0;
    const float4* mp = (const float4*)(mw + (size_t)(n0 + mm) * 16);
#pragma unroll
    for (int i = 0; i < 4; ++i) {
      float4 t4 = mp[i];
      mwr[4 * i] = t4.x; mwr[4 * i + 1] = t4.y; mwr[4 * i + 2] = t4.z; mwr[4 * i + 3] = t4.w;
    }
  }
  __syncthreads();

  if (tid < 64 && m < nvalid) {  // s combine (f64)
    double s = sdd[m][16] + ubd[16];
#pragma unroll
    for (int c = 0; c < 16; ++c) s += (sdd[m][c] + ubd[c]) * (double)mwr[c];
    s64[n0 + m] = s * (1.0 / 1024.0);
  }

  for (int p = 0; p < 11; ++p) {
    if (p == 8) __syncthreads();          // betaAcc complete before finalize
    int c0 = p * 64 + (j << 4);
    if (c0 >= 672) continue;
    const f16v* wb = (const f16v*)Wq + (c0 >> 2);   // f16v idx: k4*176 + c0/4
    float acc[16];
    {
      const f16v* wkb = wb + 32 * 176;    // bias row (k=128; element 0 of each col)
      f16v b0 = wkb[0], b1 = wkb[1], b2 = wkb[2], b3 = wkb[3];
#pragma unroll
      for (int c = 0; c < 4; ++c) {
        acc[c]      = b0[4 * c];
        acc[4 + c]  = b1[4 * c];
        acc[8 + c]  = b2[4 * c];
        acc[12 + c] = b3[4 * c];
      }
    }
    for (int k4 = 0; k4 < 32; ++k4) {
      float4 xf = xl[(m << 5) + ((k4 + m) & 31)];
      const f16v* wk = wb + k4 * 176;
      f16v w0 = wk[0], w1 = wk[1], w2 = wk[2], w3 = wk[3];
      FMA4(w0, 0) FMA4(w1, 4) FMA4(w2, 8) FMA4(w3, 12)
    }
    if (p < 8) {                          // beta cols: t = 4p+j
      float bs = 0.f;
#pragma unroll
      for (int c = 0; c < 16; ++c) bs = fmaf(acc[c], mwr[c], bs);
      betaAcc[m][4 * p + j] = bs;
    } else if (p == 8 && j < 2) {         // p-cols: finalize t = 16j..16j+15
      if (m < nvalid) {
        float* bout = beta + (size_t)(n0 + m) * NSTEP + (j << 4);
#pragma unroll
        for (int c = 0; c < 16; ++c)
          bout[c] = (betaAcc[m][(j << 4) + c] + acc[c]) * (1.f / 32.f);
      }
    } else {                              // V cols
      int vc0 = (p == 8) ? ((j - 2) << 4) : (p == 9 ? 32 + (j << 4) : 96 + (j << 4));
      if (vc0 < 128 && m < nvalid) {
        float* vout = V + (size_t)(n0 + m) * OC + vc0;
#pragma unroll
        for (int q = 0; q < 4; ++q) {
          float4 o;
          o.x = fmaxf(acc[4 * q], 0.f);     o.y = fmaxf(acc[4 * q + 1], 0.f);
          o.z = fmaxf(acc[4 * q + 2], 0.f); o.w = fmaxf(acc[4 * q + 3], 0.f);
          ((float4*)vout)[q] = o;
        }
      }
    }
  }
}

// ---------------------------------------------------------------- edge keys
__global__ void k_key(const int* __restrict__ ei, const float* __restrict__ ew,
                      const double* __restrict__ s64, unsigned long long* __restrict__ keys) {
  int e = blockIdx.x * 256 + threadIdx.x;
  if (e >= NE) return;
  int d = ei[NE + e];
  double v = s64[d] * (double)ew[e];
  unsigned long long u = (unsigned long long)__double_as_longlong(v);
  u = (u & 0x8000000000000000ull) ? ~u : (u | 0x8000000000000000ull);
  keys[e] = u;
}

// ------------------- radix select pass (hist + parallel suffix-scan pick)
__global__ void k_radix(const unsigned long long* __restrict__ keys,
                        unsigned* __restrict__ hist, SelState* st, int p) {
  __shared__ unsigned h[256], suf[256];
  __shared__ int last;
  int tid = threadIdx.x;
  h[tid] = 0u;
  if (tid == 0) last = 0;
  unsigned long long pref = (p == 0) ? 0ull : st->prefix;
  __syncthreads();
  int shift = 56 - 8 * p;
  unsigned* hp = hist + p * 256;
  for (int e = blockIdx.x * 256 + tid; e < NE; e += gridDim.x * 256) {
    unsigned long long k = keys[e];
    if (p == 0 || (k >> (shift + 8)) == pref)
      atomicAdd(&h[(unsigned)((k >> shift) & 255ull)], 1u);
  }
  __syncthreads();
  if (h[tid]) atomicAdd(&hp[tid], h[tid]);
  __threadfence();
  __syncthreads();
  if (tid == 0) {
    unsigned old = atomicAdd(&st->done[p], 1u);
    if (old == gridDim.x - 1) last = 1;
  }
  __syncthreads();
  if (!last) return;
  unsigned c = atomicAdd(&hp[tid], 0u);
  suf[tid] = c;
  __syncthreads();
  for (int d = 1; d < 256; d <<= 1) {
    unsigned v = (tid + d < 256) ? suf[tid + d] : 0u;
    __syncthreads();
    suf[tid] += v;
    __syncthreads();
  }
  unsigned r = st->r;
  unsigned exc = suf[tid] - c;
  if (exc < r && exc + c >= r) {
    st->prefix = (st->prefix << 8) | (unsigned long long)tid;
    st->r = r - exc;
  }
}

// ------------------- collect candidates matching the 16-bit prefix
__global__ void k_cand(const unsigned long long* __restrict__ keys, SelState* st,
                       unsigned long long* __restrict__ candk, int* __restrict__ cande) {
  int e = blockIdx.x * 256 + threadIdx.x;
  if (e >= NE) return;
  unsigned long long k = keys[e];
  if ((unsigned)(k >> 48) == (unsigned)st->prefix) {
    unsigned pos = atomicAdd(&st->tiec, 1u);
    if (pos < CANDCAP) { candk[pos] = k; cande[pos] = e; }
  }
}

// ----------- single block: resolve bytes 2..7 over candidates + tie select
__global__ void k_sel(const unsigned long long* __restrict__ candk,
                      const int* __restrict__ cande, const int* __restrict__ ei,
                      SelState* st, int* __restrict__ sel, unsigned* __restrict__ cnt) {
  __shared__ unsigned h[256], suf[256];
  __shared__ unsigned long long spref;
  __shared__ unsigned sr;
  int tid = threadIdx.x;
  unsigned C = st->tiec; if (C > CANDCAP) C = CANDCAP;
  if (tid == 0) { spref = st->prefix; sr = st->r; }
  __syncthreads();
  for (int p = 2; p < 8; ++p) {
    h[tid] = 0u;
    __syncthreads();
    int shift = 56 - 8 * p;
    unsigned long long pf = spref;
    unsigned r = sr;
    for (unsigned i = tid; i < C; i += 256) {
      unsigned long long k = candk[i];
      if ((k >> (shift + 8)) == pf) atomicAdd(&h[(unsigned)((k >> shift) & 255ull)], 1u);
    }
    __syncthreads();
    suf[tid] = h[tid];
    __syncthreads();
    for (int d = 1; d < 256; d <<= 1) {
      unsigned v = (tid + d < 256) ? suf[tid + d] : 0u;
      __syncthreads();
      suf[tid] += v;
      __syncthreads();
    }
    unsigned exc = suf[tid] - h[tid];
    if (exc < r && exc + h[tid] >= r) {
      spref = (pf << 8) | (unsigned long long)tid;
      sr = r - exc;
    }
    __syncthreads();
  }
  unsigned long long T = spref;
  unsigned needed = sr;
  if (tid == 0) { st->prefix = T; st->r = needed; }
  // ties: take lowest-index `needed` among keys == T
  for (unsigned i = tid; i < C; i += 256) {
    if (candk[i] == T) {
      int e = cande[i];
      unsigned rank = 0;
      for (unsigned q = 0; q < C; ++q)
        rank += (candk[q] == T && cande[q] < e) ? 1u : 0u;
      if (rank < needed) {
        unsigned pos = atomicAdd(&st->selc, 1u);
        if (pos < KSEL) { sel[pos] = e; atomicAdd(&cnt[ei[e]], 1u); }
      }
    }
  }
}

// --------------------------------------------------- selection (> T) + counts
__global__ void k_compact(const unsigned long long* __restrict__ keys,
                          const int* __restrict__ ei, SelState* st,
                          int* __restrict__ sel, unsigned* __restrict__ cnt) {
  int e = blockIdx.x * 256 + threadIdx.x;
  if (e >= NE) return;
  if (keys[e] > st->prefix) {
    unsigned pos = atomicAdd(&st->selc, 1u);
    if (pos < KSEL) { sel[pos] = e; atomicAdd(&cnt[ei[e]], 1u); }
  }
}

// ----------------------------------------------- 3-phase prefix sum -> CSR
__global__ void k_pref1(const unsigned* __restrict__ cnt, unsigned* __restrict__ bsum) {
  __shared__ unsigned sd[256];
  int i = blockIdx.x * 256 + threadIdx.x;
  sd[threadIdx.x] = (i < NN) ? cnt[i] : 0u;
  __syncthreads();
  for (int s = 128; s > 0; s >>= 1) {
    if (threadIdx.x < s) sd[threadIdx.x] += sd[threadIdx.x + s];
    __syncthreads();
  }
  if (threadIdx.x == 0) bsum[blockIdx.x] = sd[0];
}

__global__ void k_pref2(const unsigned* __restrict__ bsum, unsigned* __restrict__ bbase,
                        unsigned* __restrict__ offar) {
  __shared__ unsigned sd[128];
  int tid = threadIdx.x;
  unsigned v = (tid < NB) ? bsum[tid] : 0u;
  sd[tid] = v;
  __syncthreads();
  for (int d = 1; d < 128; d <<= 1) {
    unsigned u = (tid >= d) ? sd[tid - d] : 0u;
    __syncthreads();
    sd[tid] += u;
    __syncthreads();
  }
  if (tid < NB) bbase[tid] = sd[tid] - v;
  if (tid == NB - 1) offar[NN] = sd[tid];
}

__global__ void k_pref3(const unsigned* __restrict__ cnt, const unsigned* __restrict__ bbase,
                        unsigned* __restrict__ offar, unsigned* __restrict__ cursor) {
  __shared__ unsigned sd[256];
  int tid = threadIdx.x;
  int i = blockIdx.x * 256 + tid;
  unsigned v = (i < NN) ? cnt[i] : 0u;
  sd[tid] = v;
  __syncthreads();
  for (int d = 1; d < 256; d <<= 1) {
    unsigned u = (tid >= d) ? sd[tid - d] : 0u;
    __syncthreads();
    sd[tid] += u;
    __syncthreads();
  }
  if (i < NN) {
    unsigned excl = bbase[blockIdx.x] + sd[tid] - v;
    offar[i] = excl;
    cursor[i] = excl;
  }
}

__global__ void k_scatter(const int* __restrict__ sel, const int* __restrict__ ei,
                          unsigned* __restrict__ cursor, int* __restrict__ csr) {
  int i = blockIdx.x * 256 + threadIdx.x;
  if (i >= KSEL) return;
  int e = sel[i];
  unsigned pos = atomicAdd(&cursor[ei[e]], 1u);
  if (pos < KSEL) csr[pos] = e;
}

// ------------------------------------- per-node softmax + weighted scatter
__global__ __launch_bounds__(128) void k_out(
    const int* __restrict__ ei, const float* __restrict__ ew,
    const float* __restrict__ beta, const float* __restrict__ V,
    const unsigned* __restrict__ offar, const int* __restrict__ csr,
    float* __restrict__ out) {
  __shared__ float m[NSTEP], den[NSTEP];
  __shared__ float g[32][NSTEP];
  __shared__ int dl[32];
  __shared__ float ewl[32];
  int n = blockIdx.x, tid = threadIdx.x;
  unsigned beg = offar[n], end = offar[n + 1];
  if (end > (unsigned)KSEL) end = KSEL;
  if (beg > end) beg = end;
  if (tid < NSTEP) {
    float mm = -INFINITY;
    for (unsigned i = beg; i < end; ++i) {
      int e = csr[i]; int d = ei[NE + e];
      float v = beta[d * NSTEP + tid] * ew[e];
      mm = fmaxf(mm, v);
    }
    m[tid] = mm;
    float dd = 0.f;
    for (unsigned i = beg; i < end; ++i) {
      int e = csr[i]; int d = ei[NE + e];
      float v = beta[d * NSTEP + tid] * ew[e];
      dd += expf(v - mm);
    }
    den[tid] = dd;
  }
  __syncthreads();
  float acc = 0.f;
  int c = tid, tq = tid >> 2;
  for (unsigned cb = beg; cb < end; cb += 32u) {
    unsigned ce = end - cb; if (ce > 32u) ce = 32u;
    if (tid < (int)ce) {
      int e = csr[cb + tid];
      dl[tid] = ei[NE + e];
      ewl[tid] = ew[e];
    }
    __syncthreads();
    for (int idx = tid; idx < (int)ce * NSTEP; idx += 128) {
      int el = idx >> 5, t = idx & 31;
      float v = beta[dl[el] * NSTEP + t] * ewl[el];
      g[el][t] = expf(v - m[t]) / den[t];
    }
    __syncthreads();
    for (int el = 0; el < (int)ce; ++el)
      acc += V[dl[el] * OC + c] * g[el][tq];
    __syncthreads();
  }
  out[n * OC + c] = acc;
}

// --------------------------------------------------------------------- host
extern "C" void kernel_launch(void* const* d_in, const int* in_sizes, int n_in,
                              void* d_out, int out_size, void* d_ws, size_t ws_size,
                              hipStream_t stream) {
  const float* x     = (const float*)d_in[0];
  const float* p_t   = (const float*)d_in[1];
  const int*   ei    = (const int*)d_in[2];
  const float* ew    = (const float*)d_in[3];
  const float* lin_w = (const float*)d_in[4];
  const float* lin_b = (const float*)d_in[5];
  const float* inc_w = (const float*)d_in[6];
  const float* inc_b = (const float*)d_in[7];
  const float* mw    = (const float*)d_in[8];
  float* out = (float*)d_out;

  char* w = (char*)d_ws;
  size_t off = 0;
  auto alloc = [&](size_t b) -> void* {
    void* p = w + off;
    off += (b + 511) & ~(size_t)511;
    return p;
  };
  float*  Wq    = (float*)alloc((size_t)33 * NQCOL * 4 * 4);
  double* Ud    = (double*)alloc((size_t)17 * IC * 8);
  double* ubd   = (double*)alloc(17 * 8);
  float*  beta  = (float*)alloc((size_t)NN * NSTEP * 4);
  double* s64   = (double*)alloc((size_t)NN * 8);
  float*  V     = (float*)alloc((size_t)NN * OC * 4);
  unsigned long long* keys  = (unsigned long long*)alloc((size_t)NE * 8);
  unsigned long long* candk = (unsigned long long*)alloc((size_t)CANDCAP * 8);
  int*      cande  = (int*)alloc((size_t)CANDCAP * 4);
  int*      sel    = (int*)alloc((size_t)KSEL * 4);
  unsigned* cnt    = (unsigned*)alloc((size_t)NN * 4);
  unsigned* offar  = (unsigned*)alloc((size_t)(NN + 1) * 4);
  unsigned* cursor = (unsigned*)alloc((size_t)NN * 4);
  int*      csr    = (int*)alloc((size_t)KSEL * 4);
  unsigned* hist   = (unsigned*)alloc(512 * 4);
  unsigned* bsum   = (unsigned*)alloc(NB * 4);
  unsigned* bbase  = (unsigned*)alloc(NB * 4);
  SelState* st     = (SelState*)alloc(sizeof(SelState));
  if (off > ws_size) return;

  int init_threads = 33 * NQCOL + 17 * IC + 17 + NN + 512 + 1;
  k_init<<<(init_threads + 255) / 256, 256, 0, stream>>>(p_t, lin_w, inc_w, inc_b,
                                                         Wq, Ud, ubd, cnt, hist, st);
  k_init2<<<1, 128, 0, stream>>>(lin_b, Wq);
  k_node<<<(NN + 63) / 64, 256, 0, stream>>>(x, mw, Wq, Ud, ubd, beta, s64, V);
  k_key<<<(NE + 255) / 256, 256, 0, stream>>>(ei, ew, s64, keys);
  k_radix<<<256, 256, 0, stream>>>(keys, hist, st, 0);
  k_radix<<<256, 256, 0, stream>>>(keys, hist, st, 1);
  k_cand<<<(NE + 255) / 256, 256, 0, stream>>>(keys, st, candk, cande);
  k_sel<<<1, 256, 0, stream>>>(candk, cande, ei, st, sel, cnt);
  k_compact<<<(NE + 255) / 256, 256, 0, stream>>>(keys, ei, st, sel, cnt);
  k_pref1<<<NB, 256, 0, stream>>>(cnt, bsum);
  k_pref2<<<1, 128, 0, stream>>>(bsum, bbase, offar);
  k_pref3<<<NB, 256, 0, stream>>>(cnt, bbase, offar, cursor);
  k_scatter<<<(KSEL + 255) / 256, 256, 0, stream>>>(sel, ei, cursor, csr);
  k_out<<<NN, 128, 0, stream>>>(ei, ew, beta, V, offar, csr, out);
}